// Round 1
// baseline (480.343 us; speedup 1.0000x reference)
//
#include <hip/hip_runtime.h>

// OccurrencePool restructured:
//   r1  = relu(W1 x + b1)                     (bf16 MFMA, 34.4 GF)
//   occ = |W3 relu(W2o relu(W1o x + b1o) + b2o)|   (bf16 MFMA, 10.2 GF)
//   M[b,o,j]   = sum_s occ[b,o,s] r1[b,j,s]   (bf16 MFMA, 4.3 GF)
//   out[b,o,c] = (sum_j M[o,j] W2[c,j] + b2[c]*sum_s occ[o,s]) / S
// feat (the 2nd 512x512 GEMM over all voxels) is never computed.

#define S_TOT 16384  // T*H*W per batch

typedef __attribute__((ext_vector_type(8))) short bf8_t;  // 8 bf16 (4 VGPRs)
typedef __attribute__((ext_vector_type(4))) short s4_t;   // 4 bf16
typedef __attribute__((ext_vector_type(4))) float f4_t;

#define MFMA __builtin_amdgcn_mfma_f32_16x16x32_bf16

__device__ __forceinline__ short f2bf(float f) {
  union { float f; unsigned u; } v; v.f = f;
  unsigned u = v.u + 0x7FFFu + ((v.u >> 16) & 1u);  // RNE
  return (short)(u >> 16);
}
__device__ __forceinline__ float bf2f(short s) {
  union { unsigned u; float f; } v;
  v.u = ((unsigned)(unsigned short)s) << 16;
  return v.f;
}

// ---------------- weight fp32 -> bf16 (regions are contiguous in ws) --------
__global__ __launch_bounds__(256) void k_convert(
    const float* __restrict__ w1, const float* __restrict__ wo1,
    const float* __restrict__ wo2, const float* __restrict__ wo3,
    short* __restrict__ dst) {
  int i = blockIdx.x * 256 + threadIdx.x;
  float v;
  if (i < 262144) v = w1[i];
  else if (i < 327680) v = wo1[i - 262144];
  else if (i < 335872) v = wo2[i - 327680];
  else if (i < 339968) v = wo3[i - 335872];
  else return;
  dst[i] = f2bf(v);
}

// ---------------- x[b][c][s] fp32  ->  xT[b][s][c] bf16 ---------------------
__global__ __launch_bounds__(256) void k_transpose(
    const float* __restrict__ x, short* __restrict__ xT) {
  __shared__ float tls[64][65];  // +1 pad: conflict-free both directions
  const int sb = blockIdx.x, cb = blockIdx.y, b = blockIdx.z;
  const int t = threadIdx.x;
  {
    const int cr = t >> 2, ss = (t & 3) * 16;
    const float* src = x + ((size_t)b * 512 + cb * 64 + cr) * S_TOT + sb * 64 + ss;
    f4_t v0 = *(const f4_t*)(src);
    f4_t v1 = *(const f4_t*)(src + 4);
    f4_t v2 = *(const f4_t*)(src + 8);
    f4_t v3 = *(const f4_t*)(src + 12);
#pragma unroll
    for (int j = 0; j < 4; ++j) {
      tls[cr][ss + j]      = v0[j];
      tls[cr][ss + 4 + j]  = v1[j];
      tls[cr][ss + 8 + j]  = v2[j];
      tls[cr][ss + 12 + j] = v3[j];
    }
  }
  __syncthreads();
  {
    const int sr = t >> 2, cs = (t & 3) * 16;
    alignas(16) short tmp[16];
#pragma unroll
    for (int j = 0; j < 16; ++j) tmp[j] = f2bf(tls[cs + j][sr]);
    short* dst = xT + ((size_t)b * S_TOT + sb * 64 + sr) * 512 + cb * 64 + cs;
    *(bf8_t*)dst       = *(const bf8_t*)&tmp[0];
    *(bf8_t*)(dst + 8) = *(const bf8_t*)&tmp[8];
  }
}

// ---------------- occ chain: 3 fused GEMMs per 128-voxel tile ---------------
// h1 = relu(Wo1 @ x + b1o) [128x128]; h2 = relu(Wo2 @ h1 + b2o) [64x128];
// occ = |Wo3 @ h2| [64x128] -> global bf16 occ[b][o][s]
__global__ __launch_bounds__(256) void k_occ(
    const short* __restrict__ xT, const short* __restrict__ wo1,
    const short* __restrict__ wo2, const short* __restrict__ wo3,
    const float* __restrict__ bo1, const float* __restrict__ bo2,
    short* __restrict__ occ) {
  __shared__ short xs[128 * 72];    // [s][k(64)+pad8]; reused as h2s[s][c8+pad]
  __shared__ short h1s[128 * 136];  // [s][c4(128)+pad8]
  const int tile = blockIdx.x, b = blockIdx.y;
  const int s0 = tile * 128;
  const int t = threadIdx.x;
  const int lane = t & 63, w = t >> 6, q = lane >> 4, li = lane & 15;
  const short* xTb = xT + ((size_t)b * S_TOT + s0) * 512;
  const int cslot = (t & 7) * 8;
  const int srow0 = t >> 3;
  const f4_t fz = {0.f, 0.f, 0.f, 0.f};

  // phase 1: h1 (A=Wo1, B=x from xs); per-wave cols s in [32w,32w+32)
  f4_t acc[8][2];
#pragma unroll
  for (int i = 0; i < 8; ++i) { acc[i][0] = fz; acc[i][1] = fz; }

  for (int k0 = 0; k0 < 512; k0 += 64) {
    __syncthreads();
#pragma unroll
    for (int j = 0; j < 4; ++j) {
      int s = srow0 + 32 * j;
      *(bf8_t*)&xs[s * 72 + cslot] =
          *(const bf8_t*)(xTb + (size_t)s * 512 + k0 + cslot);
    }
    __syncthreads();
#pragma unroll
    for (int kk = 0; kk < 2; ++kk) {
      const int kb = kk * 32 + q * 8;
      bf8_t bfr[2];
#pragma unroll
      for (int nf = 0; nf < 2; ++nf)
        bfr[nf] = *(const bf8_t*)&xs[(32 * w + 16 * nf + li) * 72 + kb];
#pragma unroll
      for (int mf = 0; mf < 8; ++mf) {
        bf8_t afr = *(const bf8_t*)(wo1 + (size_t)(16 * mf + li) * 512 + k0 + kb);
        acc[mf][0] = MFMA(afr, bfr[0], acc[mf][0], 0, 0, 0);
        acc[mf][1] = MFMA(afr, bfr[1], acc[mf][1], 0, 0, 0);
      }
    }
  }
  // bias+relu -> h1s[s][c4]  (rows s are per-wave private; no barrier needed)
#pragma unroll
  for (int mf = 0; mf < 8; ++mf) {
    f4_t bv = *(const f4_t*)(bo1 + 16 * mf + 4 * q);
#pragma unroll
    for (int nf = 0; nf < 2; ++nf) {
      int s = 32 * w + 16 * nf + li;
      s4_t p;
#pragma unroll
      for (int r = 0; r < 4; ++r) p[r] = f2bf(fmaxf(acc[mf][nf][r] + bv[r], 0.0f));
      *(s4_t*)&h1s[s * 136 + 16 * mf + 4 * q] = p;
    }
  }
  // phase 2: h2 = relu(Wo2 @ h1 + b2o)
  f4_t a2[4][2];
#pragma unroll
  for (int i = 0; i < 4; ++i) { a2[i][0] = fz; a2[i][1] = fz; }
#pragma unroll
  for (int kk = 0; kk < 4; ++kk) {
    const int kb = kk * 32 + q * 8;
    bf8_t bfr[2];
#pragma unroll
    for (int nf = 0; nf < 2; ++nf)
      bfr[nf] = *(const bf8_t*)&h1s[(32 * w + 16 * nf + li) * 136 + kb];
#pragma unroll
    for (int mf = 0; mf < 4; ++mf) {
      bf8_t afr = *(const bf8_t*)(wo2 + (size_t)(16 * mf + li) * 128 + kb);
      a2[mf][0] = MFMA(afr, bfr[0], a2[mf][0], 0, 0, 0);
      a2[mf][1] = MFMA(afr, bfr[1], a2[mf][1], 0, 0, 0);
    }
  }
  // h2 -> xs reused as [s][c8(64)+pad8] (per-wave private rows)
#pragma unroll
  for (int mf = 0; mf < 4; ++mf) {
    f4_t bv = *(const f4_t*)(bo2 + 16 * mf + 4 * q);
#pragma unroll
    for (int nf = 0; nf < 2; ++nf) {
      int s = 32 * w + 16 * nf + li;
      s4_t p;
#pragma unroll
      for (int r = 0; r < 4; ++r) p[r] = f2bf(fmaxf(a2[mf][nf][r] + bv[r], 0.0f));
      *(s4_t*)&xs[s * 72 + 16 * mf + 4 * q] = p;
    }
  }
  // phase 3: occ = |Wo3 @ h2|
  f4_t a3[4][2];
#pragma unroll
  for (int i = 0; i < 4; ++i) { a3[i][0] = fz; a3[i][1] = fz; }
#pragma unroll
  for (int kk = 0; kk < 2; ++kk) {
    const int kb = kk * 32 + q * 8;
    bf8_t bfr[2];
#pragma unroll
    for (int nf = 0; nf < 2; ++nf)
      bfr[nf] = *(const bf8_t*)&xs[(32 * w + 16 * nf + li) * 72 + kb];
#pragma unroll
    for (int mf = 0; mf < 4; ++mf) {
      bf8_t afr = *(const bf8_t*)(wo3 + (size_t)(16 * mf + li) * 64 + kb);
      a3[mf][0] = MFMA(afr, bfr[0], a3[mf][0], 0, 0, 0);
      a3[mf][1] = MFMA(afr, bfr[1], a3[mf][1], 0, 0, 0);
    }
  }
#pragma unroll
  for (int mf = 0; mf < 4; ++mf)
#pragma unroll
    for (int nf = 0; nf < 2; ++nf) {
      int o = 16 * mf + 4 * q;
      int s = s0 + 32 * w + 16 * nf + li;
#pragma unroll
      for (int r = 0; r < 4; ++r)
        occ[((size_t)(b * 64 + o + r)) * S_TOT + s] = f2bf(fabsf(a3[mf][nf][r]));
    }
}

// ---------------- r1^T GEMM + spatial contraction into M --------------------
// per (b, cb=128-chan block, 256-voxel group): 2 tiles of 128 voxels
//   r1^T[s][j] = relu(x^T W1^T + b1)   (A = x^T from xs, B = W1^T from global)
//   M[o][j]   += occ[o][s] r1^T[s][j]  (A = occ from global, B = r1s[j][s])
__global__ __launch_bounds__(256) void k_feat(
    const short* __restrict__ xT, const short* __restrict__ w1,
    const float* __restrict__ b1, const short* __restrict__ occ,
    float* __restrict__ M) {
  __shared__ short xs[128 * 72];    // [s][k(64)+pad8]
  __shared__ short r1s[128 * 136];  // [j][s(128)+pad8]
  const int sg = blockIdx.x, cb = blockIdx.y, b = blockIdx.z;
  const int t = threadIdx.x;
  const int lane = t & 63, w = t >> 6, q = lane >> 4, li = lane & 15;
  const int cslot = (t & 7) * 8;
  const int srow0 = t >> 3;
  const f4_t fz = {0.f, 0.f, 0.f, 0.f};

  f4_t macc[4][2];
#pragma unroll
  for (int i = 0; i < 4; ++i) { macc[i][0] = fz; macc[i][1] = fz; }
  float biasv[2];
#pragma unroll
  for (int nf = 0; nf < 2; ++nf) biasv[nf] = b1[cb * 128 + 32 * w + 16 * nf + li];

  for (int tt = 0; tt < 2; ++tt) {
    const int s_t = sg * 256 + tt * 128;
    const short* xTs = xT + ((size_t)b * S_TOT + s_t) * 512;
    f4_t acc[8][2];
#pragma unroll
    for (int i = 0; i < 8; ++i) { acc[i][0] = fz; acc[i][1] = fz; }

    for (int k0 = 0; k0 < 512; k0 += 64) {
      __syncthreads();
#pragma unroll
      for (int j = 0; j < 4; ++j) {
        int s = srow0 + 32 * j;
        *(bf8_t*)&xs[s * 72 + cslot] =
            *(const bf8_t*)(xTs + (size_t)s * 512 + k0 + cslot);
      }
      __syncthreads();
#pragma unroll
      for (int kk = 0; kk < 2; ++kk) {
        const int kb = kk * 32 + q * 8;
        bf8_t bfr[2];
#pragma unroll
        for (int nf = 0; nf < 2; ++nf)
          bfr[nf] = *(const bf8_t*)(w1 +
              (size_t)(cb * 128 + 32 * w + 16 * nf + li) * 512 + k0 + kb);
#pragma unroll
        for (int mf = 0; mf < 8; ++mf) {
          bf8_t afr = *(const bf8_t*)&xs[(16 * mf + li) * 72 + kb];
          acc[mf][0] = MFMA(afr, bfr[0], acc[mf][0], 0, 0, 0);
          acc[mf][1] = MFMA(afr, bfr[1], acc[mf][1], 0, 0, 0);
        }
      }
    }
    // bias+relu -> r1s[j][s]; C-layout gives 4 consecutive s per lane -> b64.
    // rows j in [32w,32w+32) are per-wave private: no barrier needed.
#pragma unroll
    for (int mf = 0; mf < 8; ++mf)
#pragma unroll
      for (int nf = 0; nf < 2; ++nf) {
        int jc = 32 * w + 16 * nf + li;
        s4_t p;
#pragma unroll
        for (int r = 0; r < 4; ++r)
          p[r] = f2bf(fmaxf(acc[mf][nf][r] + biasv[nf], 0.0f));
        *(s4_t*)&r1s[jc * 136 + 16 * mf + 4 * q] = p;
      }
    // contraction over this tile's 128 voxels
    const short* ob = occ + (size_t)b * 64 * S_TOT + s_t;
#pragma unroll
    for (int kk = 0; kk < 4; ++kk) {
      const int kb = kk * 32 + q * 8;
      bf8_t bfr[2];
#pragma unroll
      for (int nf = 0; nf < 2; ++nf)
        bfr[nf] = *(const bf8_t*)&r1s[(32 * w + 16 * nf + li) * 136 + kb];
#pragma unroll
      for (int mf = 0; mf < 4; ++mf) {
        bf8_t afr = *(const bf8_t*)(ob + (size_t)(16 * mf + li) * S_TOT + kb);
        macc[mf][0] = MFMA(afr, bfr[0], macc[mf][0], 0, 0, 0);
        macc[mf][1] = MFMA(afr, bfr[1], macc[mf][1], 0, 0, 0);
      }
    }
  }
  // flush partial M (64 x 128 per wg) once
#pragma unroll
  for (int mf = 0; mf < 4; ++mf)
#pragma unroll
    for (int nf = 0; nf < 2; ++nf) {
      int jg = cb * 128 + 32 * w + 16 * nf + li;
#pragma unroll
      for (int r = 0; r < 4; ++r) {
        int o = 16 * mf + 4 * q + r;
        atomicAdd(&M[((size_t)b * 64 + o) * 512 + jg], macc[mf][nf][r]);
      }
    }
}

// ---------------- epilogue: out = (M @ W2^T + sum_occ * b2^T) / S -----------
__global__ __launch_bounds__(256) void k_epi(
    const short* __restrict__ occ, const float* __restrict__ M,
    const float* __restrict__ w2, const float* __restrict__ b2,
    float* __restrict__ out) {
  __shared__ float mrow[512];
  __shared__ float red[4];
  const int o = blockIdx.x, b = blockIdx.y;
  const int t = threadIdx.x;
  const short* orow = occ + ((size_t)b * 64 + o) * S_TOT;
  float s = 0.0f;
  for (int i = t * 8; i < S_TOT; i += 2048) {
    bf8_t v = *(const bf8_t*)(orow + i);
#pragma unroll
    for (int k = 0; k < 8; ++k) s += bf2f(v[k]);
  }
#pragma unroll
  for (int off = 32; off > 0; off >>= 1) s += __shfl_down(s, off);
  if ((t & 63) == 0) red[t >> 6] = s;
  for (int i = t; i < 512; i += 256) mrow[i] = M[((size_t)b * 64 + o) * 512 + i];
  __syncthreads();
  const float so = red[0] + red[1] + red[2] + red[3];
  for (int c = t; c < 512; c += 256) {
    const float* wr = w2 + (size_t)c * 512;
    float a = 0.0f;
    for (int jj = 0; jj < 512; jj += 4) {
      f4_t wv = *(const f4_t*)(wr + jj);
      a += wv[0] * mrow[jj] + wv[1] * mrow[jj + 1] +
           wv[2] * mrow[jj + 2] + wv[3] * mrow[jj + 3];
    }
    out[((size_t)b * 64 + o) * 512 + c] = (a + so * b2[c]) * (1.0f / 16384.0f);
  }
}

// ---------------- launch ----------------------------------------------------
// ws layout (bytes):
//   0         xT   4*16384*512 bf16  = 67108864
//   67108864  wb   339968 bf16 (w_add1 | w_occ1 | w_occ2 | w_occ3) = 679936
//   67788800  occ  4*64*16384 bf16   = 8388608
//   76177408  M    4*64*512 fp32     = 524288
//   total 76701696 bytes (~73.2 MiB)
extern "C" void kernel_launch(void* const* d_in, const int* in_sizes, int n_in,
                              void* d_out, int out_size, void* d_ws, size_t ws_size,
                              hipStream_t stream) {
  (void)in_sizes; (void)n_in; (void)out_size; (void)ws_size;
  const float* x      = (const float*)d_in[0];
  const float* w_add1 = (const float*)d_in[1];
  const float* b_add1 = (const float*)d_in[2];
  const float* w_add2 = (const float*)d_in[3];
  const float* b_add2 = (const float*)d_in[4];
  const float* w_occ1 = (const float*)d_in[5];
  const float* b_occ1 = (const float*)d_in[6];
  const float* w_occ2 = (const float*)d_in[7];
  const float* b_occ2 = (const float*)d_in[8];
  const float* w_occ3 = (const float*)d_in[9];

  char* ws = (char*)d_ws;
  short* xT  = (short*)(ws);
  short* wb  = (short*)(ws + 67108864);
  short* occ = (short*)(ws + 67788800);
  float* M   = (float*)(ws + 76177408);

  hipMemsetAsync(M, 0, 4 * 64 * 512 * sizeof(float), stream);
  k_convert<<<dim3(1328), dim3(256), 0, stream>>>(w_add1, w_occ1, w_occ2, w_occ3, wb);
  k_transpose<<<dim3(256, 8, 4), dim3(256), 0, stream>>>(x, xT);

  const short* wb1  = wb;
  const short* wbo1 = wb + 262144;
  const short* wbo2 = wb + 327680;
  const short* wbo3 = wb + 335872;
  k_occ<<<dim3(128, 4), dim3(256), 0, stream>>>(xT, wbo1, wbo2, wbo3,
                                                b_occ1, b_occ2, occ);
  k_feat<<<dim3(64, 4, 4), dim3(256), 0, stream>>>(xT, wb1, b_add1, occ, M);
  k_epi<<<dim3(64, 4), dim3(256), 0, stream>>>(occ, M, w_add2, b_add2,
                                               (float*)d_out);
}

// Round 2
// 416.634 us; speedup vs baseline: 1.1529x; 1.1529x over previous
//
#include <hip/hip_runtime.h>

// OccurrencePool restructured:
//   r1  = relu(W1 x + b1)                          (bf16 MFMA, 34.4 GF)
//   occ = |W3 relu(W2o relu(W1o x + b1o) + b2o)|   (bf16 MFMA, 10.2 GF)
//   M[b,o,j]   = sum_s occ[b,o,s] r1[b,j,s]        (bf16 MFMA, 4.3 GF)
//   out[b,o,c] = (sum_j M[o,j] W2[c,j] + b2[c]*sum_s occ[o,s]) / S
// R2: m97-style K-loops — global_load_lds(16B) staging of BOTH operands,
// chunk-planar LDS layout (slot = kchunk*128 + row) so fragment ds_read_b128
// is 2-way-bank-free without padding (glds requires lane-contiguous dests).

#define S_TOT 16384  // T*H*W per batch

typedef __attribute__((ext_vector_type(8))) short bf8_t;  // 8 bf16 (4 VGPRs)
typedef __attribute__((ext_vector_type(4))) short s4_t;   // 4 bf16
typedef __attribute__((ext_vector_type(4))) float f4_t;

#define MFMA __builtin_amdgcn_mfma_f32_16x16x32_bf16

__device__ __forceinline__ short f2bf(float f) {
  union { float f; unsigned u; } v; v.f = f;
  unsigned u = v.u + 0x7FFFu + ((v.u >> 16) & 1u);  // RNE
  return (short)(u >> 16);
}
__device__ __forceinline__ float bf2f(short s) {
  union { unsigned u; float f; } v;
  v.u = ((unsigned)(unsigned short)s) << 16;
  return v.f;
}

__device__ __forceinline__ void glds16(const void* g, void* l) {
  __builtin_amdgcn_global_load_lds(
      (const __attribute__((address_space(1))) void*)g,
      (__attribute__((address_space(3))) void*)l, 16, 0, 0);
}

// Stage a 128-row x 64-short tile (global row stride 512 shorts) into planar
// LDS: slot = c*128 + r (16B slots), c = k-chunk (0..7), r = row. Each wave
// issues 4 glds; HW scatters to base + lane*16 => slot0+lane = (c, r0+lane).
__device__ __forceinline__ void stage_tile(const short* gbase, short* lds,
                                           int wv, int lane) {
#pragma unroll
  for (int i = 0; i < 4; ++i) {
    const int slot0 = wv * 256 + i * 64;
    const int c = slot0 >> 7;
    const int r = (slot0 & 127) + lane;
    glds16(gbase + (size_t)r * 512 + c * 8, lds + slot0 * 8);
  }
}

// ---------------- weight fp32 -> bf16 (regions contiguous in ws) ------------
__global__ __launch_bounds__(256) void k_convert(
    const float* __restrict__ w1, const float* __restrict__ wo1,
    const float* __restrict__ wo2, const float* __restrict__ wo3,
    short* __restrict__ dst) {
  int i = blockIdx.x * 256 + threadIdx.x;
  float v;
  if (i < 262144) v = w1[i];
  else if (i < 327680) v = wo1[i - 262144];
  else if (i < 335872) v = wo2[i - 327680];
  else if (i < 339968) v = wo3[i - 335872];
  else return;
  dst[i] = f2bf(v);
}

// ---------------- x[b][c][s] fp32  ->  xT[b][s][c] bf16 ---------------------
__global__ __launch_bounds__(256) void k_transpose(
    const float* __restrict__ x, short* __restrict__ xT) {
  __shared__ float tls[64][65];
  const int sb = blockIdx.x, cb = blockIdx.y, b = blockIdx.z;
  const int t = threadIdx.x;
  {
    const int cr = t >> 2, ss = (t & 3) * 16;
    const float* src = x + ((size_t)b * 512 + cb * 64 + cr) * S_TOT + sb * 64 + ss;
    f4_t v0 = *(const f4_t*)(src);
    f4_t v1 = *(const f4_t*)(src + 4);
    f4_t v2 = *(const f4_t*)(src + 8);
    f4_t v3 = *(const f4_t*)(src + 12);
#pragma unroll
    for (int j = 0; j < 4; ++j) {
      tls[cr][ss + j]      = v0[j];
      tls[cr][ss + 4 + j]  = v1[j];
      tls[cr][ss + 8 + j]  = v2[j];
      tls[cr][ss + 12 + j] = v3[j];
    }
  }
  __syncthreads();
  {
    const int sr = t >> 2, cs = (t & 3) * 16;
    alignas(16) short tmp[16];
#pragma unroll
    for (int j = 0; j < 16; ++j) tmp[j] = f2bf(tls[cs + j][sr]);
    short* dst = xT + ((size_t)b * S_TOT + sb * 64 + sr) * 512 + cb * 64 + cs;
    *(bf8_t*)dst       = *(const bf8_t*)&tmp[0];
    *(bf8_t*)(dst + 8) = *(const bf8_t*)&tmp[8];
  }
}

// ---------------- occ chain: 3 fused GEMMs per 128-voxel tile ---------------
__global__ __launch_bounds__(256) void k_occ(
    const short* __restrict__ xT, const short* __restrict__ wo1,
    const short* __restrict__ wo2, const short* __restrict__ wo3,
    const float* __restrict__ bo1, const float* __restrict__ bo2,
    short* __restrict__ occ) {
  // xs 16KB (x tile / later h2s) | ws 16KB (wo1 tile) | h1s 32KB
  __shared__ short smem[32768];
  short* xs  = smem;
  short* ws  = smem + 8192;
  short* h1s = smem + 16384;
  const int tile = blockIdx.x, b = blockIdx.y;
  const int s0 = tile * 128;
  const int t = threadIdx.x, lane = t & 63, wv = t >> 6;
  const int q = lane >> 4, li = lane & 15;
  const int mh = (wv & 1) * 64, nh = (wv >> 1) * 64;
  const short* xTb = xT + ((size_t)b * S_TOT + s0) * 512;
  const f4_t fz = {0.f, 0.f, 0.f, 0.f};

  // phase 1: h1 = relu(Wo1 @ x + b1o)  [c4=128 x s=128], K=512
  f4_t acc[4][4];
#pragma unroll
  for (int i = 0; i < 4; ++i)
#pragma unroll
    for (int j = 0; j < 4; ++j) acc[i][j] = fz;

  for (int k0 = 0; k0 < 512; k0 += 64) {
    __syncthreads();
    stage_tile(xTb + k0, xs, wv, lane);   // rows: s
    stage_tile(wo1 + k0, ws, wv, lane);   // rows: c4
    __syncthreads();
#pragma unroll
    for (int kk = 0; kk < 2; ++kk) {
      const int pl = (4 * kk + q) * 128;
      bf8_t a[4], bb[4];
#pragma unroll
      for (int ma = 0; ma < 4; ++ma)
        a[ma] = *(const bf8_t*)&ws[(pl + mh + 16 * ma + li) * 8];
#pragma unroll
      for (int nb = 0; nb < 4; ++nb)
        bb[nb] = *(const bf8_t*)&xs[(pl + nh + 16 * nb + li) * 8];
#pragma unroll
      for (int ma = 0; ma < 4; ++ma)
#pragma unroll
        for (int nb = 0; nb < 4; ++nb)
          acc[ma][nb] = MFMA(a[ma], bb[nb], acc[ma][nb], 0, 0, 0);
    }
  }
  __syncthreads();
  // bias+relu -> h1s planar [c4-chunk][s]
#pragma unroll
  for (int ma = 0; ma < 4; ++ma) {
    const int c40 = mh + 16 * ma + 4 * q;
    f4_t bv = *(const f4_t*)(bo1 + c40);
#pragma unroll
    for (int nb = 0; nb < 4; ++nb) {
      const int sl = nh + 16 * nb + li;
      s4_t p;
#pragma unroll
      for (int r = 0; r < 4; ++r) p[r] = f2bf(fmaxf(acc[ma][nb][r] + bv[r], 0.0f));
      *(s4_t*)&h1s[((c40 >> 3) * 128 + sl) * 8 + (c40 & 7)] = p;
    }
  }
  __syncthreads();
  // phase 2: h2 = relu(Wo2 @ h1 + b2o)  [c8=64 x s=128], K=c4=128
  f4_t a2[4][2];
#pragma unroll
  for (int i = 0; i < 4; ++i) { a2[i][0] = fz; a2[i][1] = fz; }
#pragma unroll
  for (int kk = 0; kk < 4; ++kk) {
    const int pl = (4 * kk + q) * 128;
    bf8_t a[4], bb[2];
#pragma unroll
    for (int ma = 0; ma < 4; ++ma)
      a[ma] = *(const bf8_t*)(wo2 + (size_t)(16 * ma + li) * 128 + kk * 32 + q * 8);
#pragma unroll
    for (int nb = 0; nb < 2; ++nb)
      bb[nb] = *(const bf8_t*)&h1s[(pl + 32 * wv + 16 * nb + li) * 8];
#pragma unroll
    for (int ma = 0; ma < 4; ++ma)
#pragma unroll
      for (int nb = 0; nb < 2; ++nb)
        a2[ma][nb] = MFMA(a[ma], bb[nb], a2[ma][nb], 0, 0, 0);
  }
  // h2 -> xs region, planar [c8-chunk][s]; wave-private in s (no barrier)
#pragma unroll
  for (int ma = 0; ma < 4; ++ma) {
    const int c80 = 16 * ma + 4 * q;
    f4_t bv = *(const f4_t*)(bo2 + c80);
#pragma unroll
    for (int nb = 0; nb < 2; ++nb) {
      const int sl = 32 * wv + 16 * nb + li;
      s4_t p;
#pragma unroll
      for (int r = 0; r < 4; ++r) p[r] = f2bf(fmaxf(a2[ma][nb][r] + bv[r], 0.0f));
      *(s4_t*)&xs[((c80 >> 3) * 128 + sl) * 8 + (c80 & 7)] = p;
    }
  }
  // phase 3: occ = |Wo3 @ h2|  [o=64 x s=128], K=c8=64
  f4_t a3[4][2];
#pragma unroll
  for (int i = 0; i < 4; ++i) { a3[i][0] = fz; a3[i][1] = fz; }
#pragma unroll
  for (int kk = 0; kk < 2; ++kk) {
    const int pl = (4 * kk + q) * 128;
    bf8_t a[4], bb[2];
#pragma unroll
    for (int ma = 0; ma < 4; ++ma)
      a[ma] = *(const bf8_t*)(wo3 + (size_t)(16 * ma + li) * 64 + kk * 32 + q * 8);
#pragma unroll
    for (int nb = 0; nb < 2; ++nb)
      bb[nb] = *(const bf8_t*)&xs[(pl + 32 * wv + 16 * nb + li) * 8];
#pragma unroll
    for (int ma = 0; ma < 4; ++ma)
#pragma unroll
      for (int nb = 0; nb < 2; ++nb)
        a3[ma][nb] = MFMA(a[ma], bb[nb], a3[ma][nb], 0, 0, 0);
  }
#pragma unroll
  for (int ma = 0; ma < 4; ++ma)
#pragma unroll
    for (int nb = 0; nb < 2; ++nb) {
      const int o = 16 * ma + 4 * q;
      const int sgl = s0 + 32 * wv + 16 * nb + li;
#pragma unroll
      for (int r = 0; r < 4; ++r)
        occ[((size_t)(b * 64 + o + r)) * S_TOT + sgl] = f2bf(fabsf(a3[ma][nb][r]));
    }
}

// ---------------- r1 GEMM + spatial contraction into M ----------------------
// block: (sg, cb, b); 4 s-tiles of 128; j-tile = 128 (cb); K = 512
__global__ __launch_bounds__(256) void k_feat(
    const short* __restrict__ xT, const short* __restrict__ w1,
    const float* __restrict__ b1, const short* __restrict__ occ,
    float* __restrict__ M) {
  __shared__ short smem[16384];  // 32KB: xs | ws in K-loop, r1s (planar) after
  short* xs  = smem;
  short* ws  = smem + 8192;
  short* r1s = smem;
  const int sg = blockIdx.x, cb = blockIdx.y, b = blockIdx.z;
  const int t = threadIdx.x, lane = t & 63, wv = t >> 6;
  const int q = lane >> 4, li = lane & 15;
  const int mh = (wv & 1) * 64, nh = (wv >> 1) * 64;
  const short* w1b = w1 + (size_t)(cb * 128) * 512;
  const f4_t fz = {0.f, 0.f, 0.f, 0.f};

  float biasv[4];
#pragma unroll
  for (int nb = 0; nb < 4; ++nb) biasv[nb] = b1[cb * 128 + nh + 16 * nb + li];

  f4_t macc[4][2];
#pragma unroll
  for (int i = 0; i < 4; ++i) { macc[i][0] = fz; macc[i][1] = fz; }

  for (int tt = 0; tt < 4; ++tt) {
    const int s_t = (sg * 4 + tt) * 128;
    const short* xTb = xT + ((size_t)b * S_TOT + s_t) * 512;
    f4_t acc[4][4];
#pragma unroll
    for (int i = 0; i < 4; ++i)
#pragma unroll
      for (int j = 0; j < 4; ++j) acc[i][j] = fz;

    for (int k0 = 0; k0 < 512; k0 += 64) {
      __syncthreads();
      stage_tile(xTb + k0, xs, wv, lane);  // rows: s
      stage_tile(w1b + k0, ws, wv, lane);  // rows: j
      __syncthreads();
#pragma unroll
      for (int kk = 0; kk < 2; ++kk) {
        const int pl = (4 * kk + q) * 128;
        bf8_t a[4], bb[4];
#pragma unroll
        for (int ma = 0; ma < 4; ++ma)
          a[ma] = *(const bf8_t*)&xs[(pl + mh + 16 * ma + li) * 8];
#pragma unroll
        for (int nb = 0; nb < 4; ++nb)
          bb[nb] = *(const bf8_t*)&ws[(pl + nh + 16 * nb + li) * 8];
#pragma unroll
        for (int ma = 0; ma < 4; ++ma)
#pragma unroll
          for (int nb = 0; nb < 4; ++nb)
            acc[ma][nb] = MFMA(a[ma], bb[nb], acc[ma][nb], 0, 0, 0);
      }
    }
    __syncthreads();  // xs/ws reads done before r1s overwrite
    // prefetch occ A-fragments (global, independent of LDS) to hide latency
    const short* ob = occ + (size_t)b * 64 * S_TOT + s_t;
    bf8_t af[4][4];
#pragma unroll
    for (int kc = 0; kc < 4; ++kc)
#pragma unroll
      for (int ma = 0; ma < 4; ++ma)
        af[ma][kc] = *(const bf8_t*)(ob + (size_t)(16 * ma + li) * S_TOT +
                                     kc * 32 + q * 8);
    // r1 = relu(acc + b1) -> r1s planar [s-chunk][j]
#pragma unroll
    for (int ma = 0; ma < 4; ++ma) {
      const int sl0 = mh + 16 * ma + 4 * q;  // 4 consecutive s
#pragma unroll
      for (int nb = 0; nb < 4; ++nb) {
        const int jl = nh + 16 * nb + li;
        s4_t p;
#pragma unroll
        for (int r = 0; r < 4; ++r)
          p[r] = f2bf(fmaxf(acc[ma][nb][r] + biasv[nb], 0.0f));
        *(s4_t*)&r1s[((sl0 >> 3) * 128 + jl) * 8 + (sl0 & 7)] = p;
      }
    }
    __syncthreads();
    // M[o][j] += occ[o][s] * r1[j][s]  (K = s = 128)
#pragma unroll
    for (int kc = 0; kc < 4; ++kc) {
      const int pl = (4 * kc + q) * 128;
      bf8_t bb[2];
#pragma unroll
      for (int nb = 0; nb < 2; ++nb)
        bb[nb] = *(const bf8_t*)&r1s[(pl + 32 * wv + 16 * nb + li) * 8];
#pragma unroll
      for (int ma = 0; ma < 4; ++ma)
#pragma unroll
        for (int nb = 0; nb < 2; ++nb)
          macc[ma][nb] = MFMA(af[ma][kc], bb[nb], macc[ma][nb], 0, 0, 0);
    }
  }
  // flush partial M (64 x 128 per block) once
#pragma unroll
  for (int ma = 0; ma < 4; ++ma)
#pragma unroll
    for (int nb = 0; nb < 2; ++nb) {
      const int jg = cb * 128 + 32 * wv + 16 * nb + li;
#pragma unroll
      for (int r = 0; r < 4; ++r) {
        const int o = 16 * ma + 4 * q + r;
        atomicAdd(&M[((size_t)b * 64 + o) * 512 + jg], macc[ma][nb][r]);
      }
    }
}

// ---------------- epilogue: out = (M @ W2^T + sum_occ * b2^T) / S -----------
__global__ __launch_bounds__(256) void k_epi(
    const short* __restrict__ occ, const float* __restrict__ M,
    const float* __restrict__ w2, const float* __restrict__ b2,
    float* __restrict__ out) {
  __shared__ float mrow[512];
  __shared__ float red[4];
  const int o = blockIdx.x, b = blockIdx.y;
  const int t = threadIdx.x;
  const short* orow = occ + ((size_t)b * 64 + o) * S_TOT;
  float s = 0.0f;
  for (int i = t * 8; i < S_TOT; i += 2048) {
    bf8_t v = *(const bf8_t*)(orow + i);
#pragma unroll
    for (int k = 0; k < 8; ++k) s += bf2f(v[k]);
  }
#pragma unroll
  for (int off = 32; off > 0; off >>= 1) s += __shfl_down(s, off);
  if ((t & 63) == 0) red[t >> 6] = s;
  for (int i = t; i < 512; i += 256) mrow[i] = M[((size_t)b * 64 + o) * 512 + i];
  __syncthreads();
  const float so = red[0] + red[1] + red[2] + red[3];
  for (int c = t; c < 512; c += 256) {
    const float* wr = w2 + (size_t)c * 512;
    float a = 0.0f;
    for (int jj = 0; jj < 512; jj += 4) {
      f4_t wv = *(const f4_t*)(wr + jj);
      a += wv[0] * mrow[jj] + wv[1] * mrow[jj + 1] +
           wv[2] * mrow[jj + 2] + wv[3] * mrow[jj + 3];
    }
    out[((size_t)b * 64 + o) * 512 + c] = (a + so * b2[c]) * (1.0f / 16384.0f);
  }
}

// ---------------- launch ----------------------------------------------------
// ws layout (bytes):
//   0         xT   4*16384*512 bf16  = 67108864
//   67108864  wb   339968 bf16 (w_add1 | w_occ1 | w_occ2 | w_occ3) = 679936
//   67788800  occ  4*64*16384 bf16   = 8388608
//   76177408  M    4*64*512 fp32     = 524288
extern "C" void kernel_launch(void* const* d_in, const int* in_sizes, int n_in,
                              void* d_out, int out_size, void* d_ws, size_t ws_size,
                              hipStream_t stream) {
  (void)in_sizes; (void)n_in; (void)out_size; (void)ws_size;
  const float* x      = (const float*)d_in[0];
  const float* w_add1 = (const float*)d_in[1];
  const float* b_add1 = (const float*)d_in[2];
  const float* w_add2 = (const float*)d_in[3];
  const float* b_add2 = (const float*)d_in[4];
  const float* w_occ1 = (const float*)d_in[5];
  const float* b_occ1 = (const float*)d_in[6];
  const float* w_occ2 = (const float*)d_in[7];
  const float* b_occ2 = (const float*)d_in[8];
  const float* w_occ3 = (const float*)d_in[9];

  char* ws = (char*)d_ws;
  short* xT  = (short*)(ws);
  short* wb  = (short*)(ws + 67108864);
  short* occ = (short*)(ws + 67788800);
  float* M   = (float*)(ws + 76177408);

  hipMemsetAsync(M, 0, 4 * 64 * 512 * sizeof(float), stream);
  k_convert<<<dim3(1328), dim3(256), 0, stream>>>(w_add1, w_occ1, w_occ2, w_occ3, wb);
  k_transpose<<<dim3(256, 8, 4), dim3(256), 0, stream>>>(x, xT);

  const short* wb1  = wb;
  const short* wbo1 = wb + 262144;
  const short* wbo2 = wb + 327680;
  const short* wbo3 = wb + 335872;
  k_occ<<<dim3(128, 4), dim3(256), 0, stream>>>(xT, wbo1, wbo2, wbo3,
                                                b_occ1, b_occ2, occ);
  k_feat<<<dim3(32, 4, 4), dim3(256), 0, stream>>>(xT, wb1, b_add1, occ, M);
  k_epi<<<dim3(64, 4), dim3(256), 0, stream>>>(occ, M, w_add2, b_add2,
                                               (float*)d_out);
}